// Round 7
// baseline (271.323 us; speedup 1.0000x reference)
//
#include <hip/hip_runtime.h>

// Problem constants (fixed by reference)
#define BB 8
#define TT 16
#define DD 1024
#define NN 16
#define KHN 8      // K (kv heads)
#define HH 128
#define SS 8192
#define NPART 16   // S-partitions in attention kernel

typedef __attribute__((ext_vector_type(8))) short bf16x8;
typedef __attribute__((ext_vector_type(4))) float f32x4;

__device__ __forceinline__ unsigned short f2bf(float f) {
  unsigned u = __builtin_bit_cast(unsigned, f);
  u += 0x7FFFu + ((u >> 16) & 1u);
  return (unsigned short)(u >> 16);
}
__device__ __forceinline__ float bf2f(unsigned short h) {
  unsigned u = ((unsigned)h) << 16;
  return __builtin_bit_cast(float, u);
}
__device__ __forceinline__ f32x4 mfma16(bf16x8 a, bf16x8 b, f32x4 c) {
  return __builtin_amdgcn_mfma_f32_16x16x32_bf16(a, b, c, 0, 0, 0);
}
// RNE pack of 2 f32 -> 2 bf16 in one VALU op (identical bits to f2bf pair).
__device__ __forceinline__ unsigned cvt_pair(float a, float b) {
  unsigned r;
  asm("v_cvt_pk_bf16_f32 %0, %1, %2" : "=v"(r) : "v"(a), "v"(b));
  return r;
}
__device__ __forceinline__ void pack4(unsigned short* dst, float a, float b, float c, float d) {
  *(uint2*)dst = make_uint2(cvt_pair(a, b), cvt_pair(c, d));
}
__device__ __forceinline__ bf16x8 cvt8(const float4& lo, const float4& hi) {
  return __builtin_bit_cast(bf16x8,
      make_uint4(cvt_pair(lo.x, lo.y), cvt_pair(lo.z, lo.w),
                 cvt_pair(hi.x, hi.y), cvt_pair(hi.z, hi.w)));
}

// ---------------------------------------------------------------------------
// Kernel P: transpose + bf16-cast all weights once. (r2-verified structure)
// ---------------------------------------------------------------------------
__global__ __launch_bounds__(256) void k_wtrans(
    const float* __restrict__ Wq, const float* __restrict__ Wk,
    const float* __restrict__ Wv, const float* __restrict__ Wo,
    unsigned short* __restrict__ Wt1, unsigned short* __restrict__ Wt2) {
  __shared__ __align__(16) unsigned short Tl[64][66];
  const int tid = threadIdx.x;
  const int z = blockIdx.z;
  const float* src; int K, N; unsigned short* dst;
  if (z == 0)      { src = Wq; K = 1024; N = 2048; dst = Wt1; }
  else if (z == 1) { src = Wk; K = 1024; N = 1024; dst = Wt1 + (size_t)2048 * 1024; }
  else if (z == 2) { src = Wv; K = 1024; N = 1024; dst = Wt1 + (size_t)3072 * 1024; }
  else             { src = Wo; K = 2048; N = 1024; dst = Wt2; }
  const int n0 = blockIdx.x * 64, k0 = blockIdx.y * 64;
  if (n0 >= N || k0 >= K) return;
  {
    const int r = tid >> 4, c4 = (tid & 15) << 2;
#pragma unroll
    for (int p = 0; p < 4; ++p) {
      const int k = p * 16 + r;
      float4 f = *(const float4*)(src + (size_t)(k0 + k) * N + n0 + c4);
      pack4(&Tl[k][c4], f.x, f.y, f.z, f.w);
    }
  }
  __syncthreads();
  {
    const int c8 = tid & 7, nb = tid >> 3;
#pragma unroll
    for (int p = 0; p < 2; ++p) {
      const int n = p * 32 + nb;
      unsigned short tmp[8];
#pragma unroll
      for (int j = 0; j < 8; ++j) tmp[j] = Tl[c8 * 8 + j][n];
      unsigned short* dp = dst + (size_t)(n0 + n) * K + k0 + c8 * 8;
      *(uint4*)dp = *(const uint4*)&tmp[0];
    }
  }
}

// ---------------------------------------------------------------------------
// Kernel A: QKV projection GEMM, LDS-free / barrier-free. (unchanged)
// ---------------------------------------------------------------------------
__global__ __launch_bounds__(256) void k_qkv_gemm(
    const float* __restrict__ x, const unsigned short* __restrict__ Wt1,
    float* __restrict__ qkv) {
  const int tid = threadIdx.x, lane = tid & 63, wv = tid >> 6;
  const int cc = lane & 15, g = lane >> 4;
  const int m0 = blockIdx.x * 32, n0 = blockIdx.y * 128;
  const int rt = wv >> 1, cb0 = (wv & 1) * 64;
  const int m = m0 + rt * 16 + cc;
  f32x4 acc[4];
#pragma unroll
  for (int i = 0; i < 4; ++i) acc[i] = (f32x4)0.0f;

#pragma unroll 4
  for (int k0 = 0; k0 < 1024; k0 += 32) {
    float4 fa = *(const float4*)(x + (size_t)m * 1024 + k0 + g * 8);
    float4 fb = *(const float4*)(x + (size_t)m * 1024 + k0 + g * 8 + 4);
    bf16x8 af = cvt8(fa, fb);
#pragma unroll
    for (int ct = 0; ct < 4; ++ct) {
      const int n = n0 + cb0 + ct * 16 + cc;
      bf16x8 bf = *(const bf16x8*)(Wt1 + (size_t)n * 1024 + k0 + g * 8);
      acc[ct] = mfma16(af, bf, acc[ct]);
    }
  }
#pragma unroll
  for (int ct = 0; ct < 4; ++ct)
#pragma unroll
    for (int r = 0; r < 4; ++r) {
      int row = m0 + rt * 16 + g * 4 + r;
      int col = n0 + cb0 + ct * 16 + cc;
      qkv[(size_t)row * 4096 + col] = acc[ct][r];
    }
}

// ---------------------------------------------------------------------------
// Kernel B: RMSNorm (q,k) + RoPE (q,k) + bf16 conversion (q,k,v). (unchanged)
// ---------------------------------------------------------------------------
__global__ __launch_bounds__(128) void k_normrope(
    const float* __restrict__ qkv, const float* __restrict__ qs,
    const float* __restrict__ ks, const int* __restrict__ seg,
    const int* __restrict__ cur_p,
    unsigned short* __restrict__ qa, unsigned short* __restrict__ ka,
    unsigned short* __restrict__ va) {
  __shared__ float lv[128];
  __shared__ float red[2];
  const int row = blockIdx.x, b = row >> 4, t = row & 15;
  const int hid = blockIdx.y;
  const int h = threadIdx.x;
  float val;
  if (hid < 16)      val = qkv[row * 4096 + hid * 128 + h];
  else if (hid < 24) val = qkv[row * 4096 + 2048 + (hid - 16) * 128 + h];
  else               val = qkv[row * 4096 + 3072 + (hid - 24) * 128 + h];

  if (hid >= 24) {
    int kh = hid - 24;
    va[((b * KHN + kh) * TT + t) * 128 + h] = f2bf(val);
    return;
  }
  float ss = val * val;
#pragma unroll
  for (int m = 1; m < 64; m <<= 1) ss += __shfl_xor(ss, m, 64);
  int wid = threadIdx.x >> 6, lane = threadIdx.x & 63;
  if (lane == 0) red[wid] = ss;
  __syncthreads();
  float mean = (red[0] + red[1]) * (1.0f / 128.0f);
  float scl = (hid < 16) ? qs[h] : ks[h];
  float nrm = val * (1.0f / sqrtf(mean + 1e-6f)) * scl;
  lv[h] = nrm;
  __syncthreads();
  float prt = lv[h ^ 64];
  const int cur = cur_p[0];
  int first = TT;
#pragma unroll
  for (int i = TT - 1; i >= 0; --i)
    if (seg[b * TT + i] != 0) first = i;
  float posf;
  if (seg[b * TT + t] != 0) posf = (float)(t - first + cur);
  else                      posf = (float)(1073741824 + cur);
  int j = h & 63;
  float inv = powf(1.0e6f, -((float)j) * (1.0f / 64.0f));
  float ang = posf * inv;
  float sn = sinf(ang), cs = cosf(ang);
  float outv = (h < 64) ? (nrm * cs - prt * sn) : (nrm * cs + prt * sn);
  if (hid < 16) {
    int kh = hid >> 1, gq = hid & 1;
    qa[((b * KHN + kh) * 32 + gq * 16 + t) * 128 + h] =
        f2bf(outv * 0.08838834764831845f);
  } else {
    int kh = hid - 16;
    ka[((b * KHN + kh) * TT + t) * 128 + h] = f2bf(outv);
  }
}

// ---------------------------------------------------------------------------
// Kernel C: flash attention partials — r2-exact data path, plus:
//  * P overlays Kl[wv] after QK^T consumes K (Pl eliminated; LDS 44.5->34.3KB)
//  * __launch_bounds__(256,3): >=12 waves/CU, ~170 VGPR cap (no spill)
//  * NPART=16 (grid 1024)
//  * v_cvt_pk_bf16_f32 on all f32->bf16 staging (10x fewer cvt VALU ops)
// ---------------------------------------------------------------------------
__global__ __launch_bounds__(256, 3) void k_attn(
    const float* __restrict__ kcache, const float* __restrict__ vcache,
    const unsigned short* __restrict__ qa, const unsigned short* __restrict__ ka,
    const unsigned short* __restrict__ va, const int* __restrict__ seg,
    const int* __restrict__ sind, const int* __restrict__ cur_p,
    float* __restrict__ partO, float* __restrict__ partML) {
  __shared__ __align__(16) unsigned short Kl[4][32][132]; // 33792 B: K tile, then P, merge scratch
  __shared__ float mls[2][32][2];
  const int tid = threadIdx.x, wv = tid >> 6, lane = tid & 63;
  const int cc = lane & 15, g = lane >> 4;
  const int pair = blockIdx.x, b = pair >> 3, kh = pair & 7;
  const int qi = blockIdx.y;
  const int cur = cur_p[0];
  const int len = cur + TT;
  int start_b = sind[b];
  if (start_b < 0) {
    int first = TT;
#pragma unroll
    for (int i = TT - 1; i >= 0; --i)
      if (seg[b * TT + i] != 0) first = i;
    start_b = first;
  }
  const int NTt = (len + 31) >> 5;
  const int L = (NTt + NPART - 1) / NPART;
  const int tlo = qi * L;
  const int thi = (tlo + L < NTt) ? (tlo + L) : NTt;

  // persistent Q fragments
  bf16x8 qf[2][4];
  {
    const unsigned short* qb = qa + ((size_t)pair * 32) * 128;
#pragma unroll
    for (int rb = 0; rb < 2; ++rb)
#pragma unroll
      for (int kk = 0; kk < 4; ++kk)
        qf[rb][kk] = *(const bf16x8*)(qb + (rb * 16 + cc) * 128 + kk * 32 + g * 8);
  }
  const float* kcb = kcache + (size_t)b * (SS * 1024) + kh * 128;
  const float* vcb = vcache + (size_t)b * (SS * 1024) + kh * 128;
  const unsigned short* knb = ka + (size_t)(b * KHN + kh) * (TT * 128);
  const unsigned short* vnb = va + (size_t)(b * KHN + kh) * (TT * 128);

  f32x4 acc[2][8];
  float mreg[2][4], lreg[2][4];
#pragma unroll
  for (int rb = 0; rb < 2; ++rb) {
#pragma unroll
    for (int hb = 0; hb < 8; ++hb) acc[rb][hb] = (f32x4)0.0f;
#pragma unroll
    for (int r = 0; r < 4; ++r) { mreg[rb][r] = -1e30f; lreg[rb][r] = 0.0f; }
  }

  for (int tile = tlo + wv; tile < thi; tile += 4) {
    const int ts0 = tile << 5;
    __builtin_amdgcn_wave_barrier();
    // ---- stage K tile (32 x 128) into Kl[wv]  (r2-verified path)
    if (ts0 + 32 <= cur) {
#pragma unroll
      for (int i = 0; i < 16; ++i) {
        int ch = lane + (i << 6);
        int r = ch >> 5, c4 = (ch & 31) << 2;
        float4 f = *(const float4*)(kcb + (size_t)(ts0 + r) * 1024 + c4);
        pack4(&Kl[wv][r][c4], f.x, f.y, f.z, f.w);
      }
    } else {
#pragma unroll
      for (int i = 0; i < 16; ++i) {
        int ch = lane + (i << 6);
        int r = ch >> 5, c4 = (ch & 31) << 2;
        int ts = ts0 + r;
        if (ts < cur) {
          float4 f = *(const float4*)(kcb + (size_t)ts * 1024 + c4);
          pack4(&Kl[wv][r][c4], f.x, f.y, f.z, f.w);
        } else {
          int tr = ts - cur; if (tr > TT - 1) tr = TT - 1;
          ushort4 u = *(const ushort4*)(knb + tr * 128 + c4);
          *(ushort4*)&Kl[wv][r][c4] = u;
        }
      }
    }
    __builtin_amdgcn_wave_barrier();
    // ---- QK^T : s[rb][cb], C layout col=kv(cc), row=q(g*4+r)
    f32x4 s[2][2];
#pragma unroll
    for (int rb = 0; rb < 2; ++rb)
#pragma unroll
      for (int cb = 0; cb < 2; ++cb) s[rb][cb] = (f32x4)0.0f;
#pragma unroll
    for (int kk = 0; kk < 4; ++kk) {
#pragma unroll
      for (int cb = 0; cb < 2; ++cb) {
        const unsigned short* kp = &Kl[wv][cb * 16 + cc][kk * 32 + g * 8];
        uint2 lo = *(const uint2*)kp;
        uint2 hi = *(const uint2*)(kp + 4);
        bf16x8 kf = __builtin_bit_cast(bf16x8, make_uint4(lo.x, lo.y, hi.x, hi.y));
        s[0][cb] = mfma16(qf[0][kk], kf, s[0][cb]);
        s[1][cb] = mfma16(qf[1][kk], kf, s[1][cb]);
      }
    }
    // ---- V fragments (direct global, issued before softmax; cvt_pk packing)
    bf16x8 vf[8];
    if (ts0 + 32 <= cur) {
#pragma unroll
      for (int hb = 0; hb < 8; ++hb) {
        const int hc = hb * 16 + cc;
        float v0 = vcb[(size_t)(ts0 + g * 8 + 0) * 1024 + hc];
        float v1 = vcb[(size_t)(ts0 + g * 8 + 1) * 1024 + hc];
        float v2 = vcb[(size_t)(ts0 + g * 8 + 2) * 1024 + hc];
        float v3 = vcb[(size_t)(ts0 + g * 8 + 3) * 1024 + hc];
        float v4 = vcb[(size_t)(ts0 + g * 8 + 4) * 1024 + hc];
        float v5 = vcb[(size_t)(ts0 + g * 8 + 5) * 1024 + hc];
        float v6 = vcb[(size_t)(ts0 + g * 8 + 6) * 1024 + hc];
        float v7 = vcb[(size_t)(ts0 + g * 8 + 7) * 1024 + hc];
        vf[hb] = __builtin_bit_cast(bf16x8,
            make_uint4(cvt_pair(v0, v1), cvt_pair(v2, v3),
                       cvt_pair(v4, v5), cvt_pair(v6, v7)));
      }
    } else {
#pragma unroll
      for (int hb = 0; hb < 8; ++hb) {
        const int hc = hb * 16 + cc;
        float vv[8];
#pragma unroll
        for (int j = 0; j < 8; ++j) {
          const int ts = ts0 + g * 8 + j;
          if (ts < cur) vv[j] = vcb[(size_t)ts * 1024 + hc];
          else { int tr = ts - cur; if (tr > TT - 1) tr = TT - 1; vv[j] = bf2f(vnb[tr * 128 + hc]); }
        }
        vf[hb] = __builtin_bit_cast(bf16x8,
            make_uint4(cvt_pair(vv[0], vv[1]), cvt_pair(vv[2], vv[3]),
                       cvt_pair(vv[4], vv[5]), cvt_pair(vv[6], vv[7])));
      }
    }
    // ---- mask + online softmax
    float al[2][4];
#pragma unroll
    for (int rb = 0; rb < 2; ++rb) {
#pragma unroll
      for (int r = 0; r < 4; ++r) {
        const int tq = g * 4 + r;
#pragma unroll
        for (int cb = 0; cb < 2; ++cb) {
          int ts = ts0 + cb * 16 + cc;
          bool ok = (ts >= start_b) && (ts <= cur + tq);
          if (!ok) s[rb][cb][r] = -1e30f;
        }
        float tm = fmaxf(s[rb][0][r], s[rb][1][r]);
#pragma unroll
        for (int m = 1; m < 16; m <<= 1) tm = fmaxf(tm, __shfl_xor(tm, m, 64));
        float mn = fmaxf(mreg[rb][r], tm);
        float a = __expf(mreg[rb][r] - mn);
        float p0 = (s[rb][0][r] < -1e29f) ? 0.0f : __expf(s[rb][0][r] - mn);
        float p1 = (s[rb][1][r] < -1e29f) ? 0.0f : __expf(s[rb][1][r] - mn);
        s[rb][0][r] = p0; s[rb][1][r] = p1;
        float rs = p0 + p1;
#pragma unroll
        for (int m = 1; m < 16; m <<= 1) rs += __shfl_xor(rs, m, 64);
        lreg[rb][r] = lreg[rb][r] * a + rs;
        mreg[rb][r] = mn;
        al[rb][r] = a;
      }
    }
    // ---- P -> Kl overlay (K is dead after QK; in-wave DS is in-order)
    __builtin_amdgcn_wave_barrier();
#pragma unroll
    for (int rb = 0; rb < 2; ++rb)
#pragma unroll
      for (int cb = 0; cb < 2; ++cb)
#pragma unroll
        for (int r = 0; r < 4; ++r)
          Kl[wv][rb * 16 + g * 4 + r][cb * 16 + cc] = f2bf(s[rb][cb][r]);
    __builtin_amdgcn_wave_barrier();
    bf16x8 pf[2];
#pragma unroll
    for (int rb = 0; rb < 2; ++rb) {
      const unsigned short* pp = &Kl[wv][rb * 16 + cc][g * 8];
      uint2 lo = *(const uint2*)pp;
      uint2 hi = *(const uint2*)(pp + 4);
      pf[rb] = __builtin_bit_cast(bf16x8, make_uint4(lo.x, lo.y, hi.x, hi.y));
    }
    // ---- rescale + PV
#pragma unroll
    for (int rb = 0; rb < 2; ++rb)
#pragma unroll
      for (int hb = 0; hb < 8; ++hb) {
        f32x4 t = acc[rb][hb];
#pragma unroll
        for (int r = 0; r < 4; ++r) t[r] *= al[rb][r];
        acc[rb][hb] = mfma16(pf[rb], vf[hb], t);
      }
  }

  // ---- merge 4 wave-partials -> 1 block partial (scratch overlays Kl)
  float* Oscr = (float*)&Kl[0][0][0]; // 2 x 32 x 128 floats = 32 KB <= 33 KB
  auto dump = [&](int sid) {
#pragma unroll
    for (int rb = 0; rb < 2; ++rb)
#pragma unroll
      for (int hb = 0; hb < 8; ++hb)
#pragma unroll
        for (int r = 0; r < 4; ++r)
          Oscr[(sid * 32 + rb * 16 + g * 4 + r) * 128 + hb * 16 + cc] = acc[rb][hb][r];
    if (cc == 0) {
#pragma unroll
      for (int rb = 0; rb < 2; ++rb)
#pragma unroll
        for (int r = 0; r < 4; ++r) {
          mls[sid][rb * 16 + g * 4 + r][0] = mreg[rb][r];
          mls[sid][rb * 16 + g * 4 + r][1] = lreg[rb][r];
        }
    }
  };
  auto mergefrom = [&](int sid) {
    float a0s[2][4], a1s[2][4];
#pragma unroll
    for (int rb = 0; rb < 2; ++rb)
#pragma unroll
      for (int r = 0; r < 4; ++r) {
        int row = rb * 16 + g * 4 + r;
        float mp = mls[sid][row][0], lp = mls[sid][row][1];
        float M = fmaxf(mreg[rb][r], mp);
        float a0 = __expf(mreg[rb][r] - M), a1 = __expf(mp - M);
        lreg[rb][r] = lreg[rb][r] * a0 + lp * a1;
        mreg[rb][r] = M;
        a0s[rb][r] = a0; a1s[rb][r] = a1;
      }
#pragma unroll
    for (int rb = 0; rb < 2; ++rb)
#pragma unroll
      for (int hb = 0; hb < 8; ++hb)
#pragma unroll
        for (int r = 0; r < 4; ++r) {
          int row = rb * 16 + g * 4 + r;
          acc[rb][hb][r] = acc[rb][hb][r] * a0s[rb][r] +
                           Oscr[(sid * 32 + row) * 128 + hb * 16 + cc] * a1s[rb][r];
        }
  };
  __syncthreads();
  if (wv >= 2) dump(wv - 2);
  __syncthreads();
  if (wv < 2) mergefrom(wv);
  __syncthreads();
  if (wv == 1) dump(0);
  __syncthreads();
  if (wv == 0) {
    mergefrom(0);
    size_t pidx = (size_t)pair * NPART + qi;
#pragma unroll
    for (int rb = 0; rb < 2; ++rb)
#pragma unroll
      for (int hb = 0; hb < 8; ++hb)
#pragma unroll
        for (int r = 0; r < 4; ++r)
          partO[(pidx * 32 + rb * 16 + g * 4 + r) * 128 + hb * 16 + cc] = acc[rb][hb][r];
    if (cc == 0) {
#pragma unroll
      for (int rb = 0; rb < 2; ++rb)
#pragma unroll
        for (int r = 0; r < 4; ++r) {
          partML[pidx * 64 + (rb * 16 + g * 4 + r) * 2 + 0] = mreg[rb][r];
          partML[pidx * 64 + (rb * 16 + g * 4 + r) * 2 + 1] = lreg[rb][r];
        }
    }
  }
}

// ---------------------------------------------------------------------------
// Kernel D1: combine NPART partials per (b,kh). grid (64, 4).
// ---------------------------------------------------------------------------
__global__ __launch_bounds__(256) void k_combine(
    const float* __restrict__ partO, const float* __restrict__ partML,
    unsigned short* __restrict__ obf) {
  __shared__ float sc[NPART][32];
  const int pair = blockIdx.x, b = pair >> 3, kh = pair & 7;
  const int isub = blockIdx.y;
  const int tid = threadIdx.x;
  if (tid < 32) {
    float mm[NPART], ll[NPART];
    float M = -3.0e38f;
#pragma unroll
    for (int p = 0; p < NPART; ++p) {
      mm[p] = partML[((size_t)pair * NPART + p) * 64 + tid * 2 + 0];
      ll[p] = partML[((size_t)pair * NPART + p) * 64 + tid * 2 + 1];
      M = fmaxf(M, mm[p]);
    }
    float denom = 0.0f;
#pragma unroll
    for (int p = 0; p < NPART; ++p) denom += __expf(mm[p] - M) * ll[p];
    float inv = (denom > 0.0f) ? 1.0f / denom : 0.0f;
#pragma unroll
    for (int p = 0; p < NPART; ++p) sc[p][tid] = __expf(mm[p] - M) * inv;
  }
  __syncthreads();
#pragma unroll
  for (int i = 0; i < 4; ++i) {
    int idx = tid + ((isub * 4 + i) << 8);
    int row = idx >> 7, hc = idx & 127;
    float o = 0.0f;
#pragma unroll
    for (int p = 0; p < NPART; ++p)
      o += partO[(((size_t)pair * NPART + p) * 32 + row) * 128 + hc] * sc[p][row];
    int gq = row >> 4, t = row & 15, n = kh * 2 + gq;
    obf[((b * TT + t) * NN + n) * 128 + hc] = f2bf(o);
  }
}

// ---------------------------------------------------------------------------
// Kernel D2: output projection, LDS-free / barrier-free. (unchanged)
// ---------------------------------------------------------------------------
__global__ __launch_bounds__(256) void k_out_gemm(
    const unsigned short* __restrict__ obf, const unsigned short* __restrict__ Wt2,
    float* __restrict__ out) {
  const int tid = threadIdx.x, lane = tid & 63, wv = tid >> 6;
  const int cc = lane & 15, g = lane >> 4;
  const int m0 = blockIdx.x * 32, n0 = blockIdx.y * 64;
  const int rt = wv >> 1, cb0 = (wv & 1) * 32;
  const int m = m0 + rt * 16 + cc;
  f32x4 acc[2];
#pragma unroll
  for (int i = 0; i < 2; ++i) acc[i] = (f32x4)0.0f;

#pragma unroll 4
  for (int k0 = 0; k0 < 2048; k0 += 32) {
    bf16x8 af = *(const bf16x8*)(obf + (size_t)m * 2048 + k0 + g * 8);
#pragma unroll
    for (int ct = 0; ct < 2; ++ct) {
      const int d = n0 + cb0 + ct * 16 + cc;
      bf16x8 bf = *(const bf16x8*)(Wt2 + (size_t)d * 2048 + k0 + g * 8);
      acc[ct] = mfma16(af, bf, acc[ct]);
    }
  }
#pragma unroll
  for (int ct = 0; ct < 2; ++ct)
#pragma unroll
    for (int r = 0; r < 4; ++r)
      out[(size_t)(m0 + rt * 16 + g * 4 + r) * 1024 + n0 + cb0 + ct * 16 + cc] = acc[ct][r];
}

// ---------------------------------------------------------------------------
extern "C" void kernel_launch(void* const* d_in, const int* in_sizes, int n_in,
                              void* d_out, int out_size, void* d_ws, size_t ws_size,
                              hipStream_t stream) {
  (void)in_sizes; (void)n_in; (void)out_size; (void)ws_size;
  const float* x   = (const float*)d_in[0];
  const float* Wq  = (const float*)d_in[1];
  const float* Wk  = (const float*)d_in[2];
  const float* Wv  = (const float*)d_in[3];
  const float* Wo  = (const float*)d_in[4];
  const float* qs  = (const float*)d_in[5];
  const float* ks  = (const float*)d_in[6];
  const float* kc  = (const float*)d_in[7];
  const float* vc  = (const float*)d_in[8];
  const int* seg   = (const int*)d_in[9];
  const int* sind  = (const int*)d_in[10];
  const int* curp  = (const int*)d_in[11];
  float* out = (float*)d_out;

  char* ws = (char*)d_ws;
  float*          qkv    = (float*)(ws + 0);                 //  2,097,152 B
  unsigned short* qa     = (unsigned short*)(ws + 2097152);  //    524,288 B
  unsigned short* ka     = (unsigned short*)(ws + 2621440);  //    262,144 B
  unsigned short* va     = (unsigned short*)(ws + 2883584);  //    262,144 B
  float*          partO  = (float*)(ws + 3145728);           // 16,777,216 B
  float*          partML = (float*)(ws + 19922944);          //    262,144 B
  unsigned short* obf    = (unsigned short*)(ws + 20185088); //    524,288 B
  unsigned short* Wt1    = (unsigned short*)(ws + 20709376); //  8,388,608 B
  unsigned short* Wt2    = (unsigned short*)(ws + 29097984); //  4,194,304 B

  k_wtrans<<<dim3(32, 32, 4), 256, 0, stream>>>(Wq, Wk, Wv, Wo, Wt1, Wt2);
  k_qkv_gemm<<<dim3(4, 32), 256, 0, stream>>>(x, Wt1, qkv);
  k_normrope<<<dim3(128, 32), 128, 0, stream>>>(qkv, qs, ks, seg, curp, qa, ka, va);
  k_attn<<<dim3(64, NPART), 256, 0, stream>>>(kc, vc, qa, ka, va, seg, sind, curp, partO, partML);
  k_combine<<<dim3(64, 4), 256, 0, stream>>>(partO, partML, obf);
  k_out_gemm<<<dim3(4, 16), 256, 0, stream>>>(obf, Wt2, out);
}

// Round 8
// 151.373 us; speedup vs baseline: 1.7924x; 1.7924x over previous
//
#include <hip/hip_runtime.h>

// Problem constants (fixed by reference)
#define BB 8
#define TT 16
#define DD 1024
#define NN 16
#define KHN 8      // K (kv heads)
#define HH 128
#define SS 8192
#define NPART 16   // S-partitions in attention kernel

typedef __attribute__((ext_vector_type(8))) short bf16x8;
typedef __attribute__((ext_vector_type(4))) float f32x4;

__device__ __forceinline__ unsigned short f2bf(float f) {
  unsigned u = __builtin_bit_cast(unsigned, f);
  u += 0x7FFFu + ((u >> 16) & 1u);
  return (unsigned short)(u >> 16);
}
__device__ __forceinline__ float bf2f(unsigned short h) {
  unsigned u = ((unsigned)h) << 16;
  return __builtin_bit_cast(float, u);
}
__device__ __forceinline__ f32x4 mfma16(bf16x8 a, bf16x8 b, f32x4 c) {
  return __builtin_amdgcn_mfma_f32_16x16x32_bf16(a, b, c, 0, 0, 0);
}
// RNE pack of 2 f32 -> 2 bf16 in one VALU op (identical bits to f2bf pair).
__device__ __forceinline__ unsigned cvt_pair(float a, float b) {
  unsigned r;
  asm("v_cvt_pk_bf16_f32 %0, %1, %2" : "=v"(r) : "v"(a), "v"(b));
  return r;
}
__device__ __forceinline__ void pack4(unsigned short* dst, float a, float b, float c, float d) {
  *(uint2*)dst = make_uint2(cvt_pair(a, b), cvt_pair(c, d));
}
__device__ __forceinline__ bf16x8 cvt8(const float4& lo, const float4& hi) {
  return __builtin_bit_cast(bf16x8,
      make_uint4(cvt_pair(lo.x, lo.y), cvt_pair(lo.z, lo.w),
                 cvt_pair(hi.x, hi.y), cvt_pair(hi.z, hi.w)));
}

// ---------------------------------------------------------------------------
// Kernel P: transpose + bf16-cast all weights once. (r2-verified structure)
// ---------------------------------------------------------------------------
__global__ __launch_bounds__(256) void k_wtrans(
    const float* __restrict__ Wq, const float* __restrict__ Wk,
    const float* __restrict__ Wv, const float* __restrict__ Wo,
    unsigned short* __restrict__ Wt1, unsigned short* __restrict__ Wt2) {
  __shared__ __align__(16) unsigned short Tl[64][66];
  const int tid = threadIdx.x;
  const int z = blockIdx.z;
  const float* src; int K, N; unsigned short* dst;
  if (z == 0)      { src = Wq; K = 1024; N = 2048; dst = Wt1; }
  else if (z == 1) { src = Wk; K = 1024; N = 1024; dst = Wt1 + (size_t)2048 * 1024; }
  else if (z == 2) { src = Wv; K = 1024; N = 1024; dst = Wt1 + (size_t)3072 * 1024; }
  else             { src = Wo; K = 2048; N = 1024; dst = Wt2; }
  const int n0 = blockIdx.x * 64, k0 = blockIdx.y * 64;
  if (n0 >= N || k0 >= K) return;
  {
    const int r = tid >> 4, c4 = (tid & 15) << 2;
#pragma unroll
    for (int p = 0; p < 4; ++p) {
      const int k = p * 16 + r;
      float4 f = *(const float4*)(src + (size_t)(k0 + k) * N + n0 + c4);
      pack4(&Tl[k][c4], f.x, f.y, f.z, f.w);
    }
  }
  __syncthreads();
  {
    const int c8 = tid & 7, nb = tid >> 3;
#pragma unroll
    for (int p = 0; p < 2; ++p) {
      const int n = p * 32 + nb;
      unsigned short tmp[8];
#pragma unroll
      for (int j = 0; j < 8; ++j) tmp[j] = Tl[c8 * 8 + j][n];
      unsigned short* dp = dst + (size_t)(n0 + n) * K + k0 + c8 * 8;
      *(uint4*)dp = *(const uint4*)&tmp[0];
    }
  }
}

// ---------------------------------------------------------------------------
// Kernel A: QKV projection GEMM, LDS-free / barrier-free. (unchanged)
// ---------------------------------------------------------------------------
__global__ __launch_bounds__(256) void k_qkv_gemm(
    const float* __restrict__ x, const unsigned short* __restrict__ Wt1,
    float* __restrict__ qkv) {
  const int tid = threadIdx.x, lane = tid & 63, wv = tid >> 6;
  const int cc = lane & 15, g = lane >> 4;
  const int m0 = blockIdx.x * 32, n0 = blockIdx.y * 128;
  const int rt = wv >> 1, cb0 = (wv & 1) * 64;
  const int m = m0 + rt * 16 + cc;
  f32x4 acc[4];
#pragma unroll
  for (int i = 0; i < 4; ++i) acc[i] = (f32x4)0.0f;

#pragma unroll 4
  for (int k0 = 0; k0 < 1024; k0 += 32) {
    float4 fa = *(const float4*)(x + (size_t)m * 1024 + k0 + g * 8);
    float4 fb = *(const float4*)(x + (size_t)m * 1024 + k0 + g * 8 + 4);
    bf16x8 af = cvt8(fa, fb);
#pragma unroll
    for (int ct = 0; ct < 4; ++ct) {
      const int n = n0 + cb0 + ct * 16 + cc;
      bf16x8 bf = *(const bf16x8*)(Wt1 + (size_t)n * 1024 + k0 + g * 8);
      acc[ct] = mfma16(af, bf, acc[ct]);
    }
  }
#pragma unroll
  for (int ct = 0; ct < 4; ++ct)
#pragma unroll
    for (int r = 0; r < 4; ++r) {
      int row = m0 + rt * 16 + g * 4 + r;
      int col = n0 + cb0 + ct * 16 + cc;
      qkv[(size_t)row * 4096 + col] = acc[ct][r];
    }
}

// ---------------------------------------------------------------------------
// Kernel B: RMSNorm (q,k) + RoPE (q,k) + bf16 conversion (q,k,v). (unchanged)
// ---------------------------------------------------------------------------
__global__ __launch_bounds__(128) void k_normrope(
    const float* __restrict__ qkv, const float* __restrict__ qs,
    const float* __restrict__ ks, const int* __restrict__ seg,
    const int* __restrict__ cur_p,
    unsigned short* __restrict__ qa, unsigned short* __restrict__ ka,
    unsigned short* __restrict__ va) {
  __shared__ float lv[128];
  __shared__ float red[2];
  const int row = blockIdx.x, b = row >> 4, t = row & 15;
  const int hid = blockIdx.y;
  const int h = threadIdx.x;
  float val;
  if (hid < 16)      val = qkv[row * 4096 + hid * 128 + h];
  else if (hid < 24) val = qkv[row * 4096 + 2048 + (hid - 16) * 128 + h];
  else               val = qkv[row * 4096 + 3072 + (hid - 24) * 128 + h];

  if (hid >= 24) {
    int kh = hid - 24;
    va[((b * KHN + kh) * TT + t) * 128 + h] = f2bf(val);
    return;
  }
  float ss = val * val;
#pragma unroll
  for (int m = 1; m < 64; m <<= 1) ss += __shfl_xor(ss, m, 64);
  int wid = threadIdx.x >> 6, lane = threadIdx.x & 63;
  if (lane == 0) red[wid] = ss;
  __syncthreads();
  float mean = (red[0] + red[1]) * (1.0f / 128.0f);
  float scl = (hid < 16) ? qs[h] : ks[h];
  float nrm = val * (1.0f / sqrtf(mean + 1e-6f)) * scl;
  lv[h] = nrm;
  __syncthreads();
  float prt = lv[h ^ 64];
  const int cur = cur_p[0];
  int first = TT;
#pragma unroll
  for (int i = TT - 1; i >= 0; --i)
    if (seg[b * TT + i] != 0) first = i;
  float posf;
  if (seg[b * TT + t] != 0) posf = (float)(t - first + cur);
  else                      posf = (float)(1073741824 + cur);
  int j = h & 63;
  float inv = powf(1.0e6f, -((float)j) * (1.0f / 64.0f));
  float ang = posf * inv;
  float sn = sinf(ang), cs = cosf(ang);
  float outv = (h < 64) ? (nrm * cs - prt * sn) : (nrm * cs + prt * sn);
  if (hid < 16) {
    int kh = hid >> 1, gq = hid & 1;
    qa[((b * KHN + kh) * 32 + gq * 16 + t) * 128 + h] =
        f2bf(outv * 0.08838834764831845f);
  } else {
    int kh = hid - 16;
    ka[((b * KHN + kh) * TT + t) * 128 + h] = f2bf(outv);
  }
}

// ---------------------------------------------------------------------------
// Kernel C: flash attention partials — identical to round 7 EXCEPT
// __launch_bounds__(256, 2): no VGPR cap below the live set (r7's 84-reg cap
// spilled acc; r4 same). Occupancy comes from grid pressure (NPART=16) +
// small LDS (34.3 KB -> up to 4 blocks/CU), not from allocator caps.
// ---------------------------------------------------------------------------
__global__ __launch_bounds__(256, 2) void k_attn(
    const float* __restrict__ kcache, const float* __restrict__ vcache,
    const unsigned short* __restrict__ qa, const unsigned short* __restrict__ ka,
    const unsigned short* __restrict__ va, const int* __restrict__ seg,
    const int* __restrict__ sind, const int* __restrict__ cur_p,
    float* __restrict__ partO, float* __restrict__ partML) {
  __shared__ __align__(16) unsigned short Kl[4][32][132]; // 33792 B: K tile, then P, merge scratch
  __shared__ float mls[2][32][2];
  const int tid = threadIdx.x, wv = tid >> 6, lane = tid & 63;
  const int cc = lane & 15, g = lane >> 4;
  const int pair = blockIdx.x, b = pair >> 3, kh = pair & 7;
  const int qi = blockIdx.y;
  const int cur = cur_p[0];
  const int len = cur + TT;
  int start_b = sind[b];
  if (start_b < 0) {
    int first = TT;
#pragma unroll
    for (int i = TT - 1; i >= 0; --i)
      if (seg[b * TT + i] != 0) first = i;
    start_b = first;
  }
  const int NTt = (len + 31) >> 5;
  const int L = (NTt + NPART - 1) / NPART;
  const int tlo = qi * L;
  const int thi = (tlo + L < NTt) ? (tlo + L) : NTt;

  // persistent Q fragments
  bf16x8 qf[2][4];
  {
    const unsigned short* qb = qa + ((size_t)pair * 32) * 128;
#pragma unroll
    for (int rb = 0; rb < 2; ++rb)
#pragma unroll
      for (int kk = 0; kk < 4; ++kk)
        qf[rb][kk] = *(const bf16x8*)(qb + (rb * 16 + cc) * 128 + kk * 32 + g * 8);
  }
  const float* kcb = kcache + (size_t)b * (SS * 1024) + kh * 128;
  const float* vcb = vcache + (size_t)b * (SS * 1024) + kh * 128;
  const unsigned short* knb = ka + (size_t)(b * KHN + kh) * (TT * 128);
  const unsigned short* vnb = va + (size_t)(b * KHN + kh) * (TT * 128);

  f32x4 acc[2][8];
  float mreg[2][4], lreg[2][4];
#pragma unroll
  for (int rb = 0; rb < 2; ++rb) {
#pragma unroll
    for (int hb = 0; hb < 8; ++hb) acc[rb][hb] = (f32x4)0.0f;
#pragma unroll
    for (int r = 0; r < 4; ++r) { mreg[rb][r] = -1e30f; lreg[rb][r] = 0.0f; }
  }

  for (int tile = tlo + wv; tile < thi; tile += 4) {
    const int ts0 = tile << 5;
    __builtin_amdgcn_wave_barrier();
    // ---- stage K tile (32 x 128) into Kl[wv]  (r2-verified path)
    if (ts0 + 32 <= cur) {
#pragma unroll
      for (int i = 0; i < 16; ++i) {
        int ch = lane + (i << 6);
        int r = ch >> 5, c4 = (ch & 31) << 2;
        float4 f = *(const float4*)(kcb + (size_t)(ts0 + r) * 1024 + c4);
        pack4(&Kl[wv][r][c4], f.x, f.y, f.z, f.w);
      }
    } else {
#pragma unroll
      for (int i = 0; i < 16; ++i) {
        int ch = lane + (i << 6);
        int r = ch >> 5, c4 = (ch & 31) << 2;
        int ts = ts0 + r;
        if (ts < cur) {
          float4 f = *(const float4*)(kcb + (size_t)ts * 1024 + c4);
          pack4(&Kl[wv][r][c4], f.x, f.y, f.z, f.w);
        } else {
          int tr = ts - cur; if (tr > TT - 1) tr = TT - 1;
          ushort4 u = *(const ushort4*)(knb + tr * 128 + c4);
          *(ushort4*)&Kl[wv][r][c4] = u;
        }
      }
    }
    __builtin_amdgcn_wave_barrier();
    // ---- QK^T : s[rb][cb], C layout col=kv(cc), row=q(g*4+r)
    f32x4 s[2][2];
#pragma unroll
    for (int rb = 0; rb < 2; ++rb)
#pragma unroll
      for (int cb = 0; cb < 2; ++cb) s[rb][cb] = (f32x4)0.0f;
#pragma unroll
    for (int kk = 0; kk < 4; ++kk) {
#pragma unroll
      for (int cb = 0; cb < 2; ++cb) {
        const unsigned short* kp = &Kl[wv][cb * 16 + cc][kk * 32 + g * 8];
        uint2 lo = *(const uint2*)kp;
        uint2 hi = *(const uint2*)(kp + 4);
        bf16x8 kf = __builtin_bit_cast(bf16x8, make_uint4(lo.x, lo.y, hi.x, hi.y));
        s[0][cb] = mfma16(qf[0][kk], kf, s[0][cb]);
        s[1][cb] = mfma16(qf[1][kk], kf, s[1][cb]);
      }
    }
    // ---- V fragments (direct global, issued before softmax; cvt_pk packing)
    bf16x8 vf[8];
    if (ts0 + 32 <= cur) {
#pragma unroll
      for (int hb = 0; hb < 8; ++hb) {
        const int hc = hb * 16 + cc;
        float v0 = vcb[(size_t)(ts0 + g * 8 + 0) * 1024 + hc];
        float v1 = vcb[(size_t)(ts0 + g * 8 + 1) * 1024 + hc];
        float v2 = vcb[(size_t)(ts0 + g * 8 + 2) * 1024 + hc];
        float v3 = vcb[(size_t)(ts0 + g * 8 + 3) * 1024 + hc];
        float v4 = vcb[(size_t)(ts0 + g * 8 + 4) * 1024 + hc];
        float v5 = vcb[(size_t)(ts0 + g * 8 + 5) * 1024 + hc];
        float v6 = vcb[(size_t)(ts0 + g * 8 + 6) * 1024 + hc];
        float v7 = vcb[(size_t)(ts0 + g * 8 + 7) * 1024 + hc];
        vf[hb] = __builtin_bit_cast(bf16x8,
            make_uint4(cvt_pair(v0, v1), cvt_pair(v2, v3),
                       cvt_pair(v4, v5), cvt_pair(v6, v7)));
      }
    } else {
#pragma unroll
      for (int hb = 0; hb < 8; ++hb) {
        const int hc = hb * 16 + cc;
        float vv[8];
#pragma unroll
        for (int j = 0; j < 8; ++j) {
          const int ts = ts0 + g * 8 + j;
          if (ts < cur) vv[j] = vcb[(size_t)ts * 1024 + hc];
          else { int tr = ts - cur; if (tr > TT - 1) tr = TT - 1; vv[j] = bf2f(vnb[tr * 128 + hc]); }
        }
        vf[hb] = __builtin_bit_cast(bf16x8,
            make_uint4(cvt_pair(vv[0], vv[1]), cvt_pair(vv[2], vv[3]),
                       cvt_pair(vv[4], vv[5]), cvt_pair(vv[6], vv[7])));
      }
    }
    // ---- mask + online softmax
    float al[2][4];
#pragma unroll
    for (int rb = 0; rb < 2; ++rb) {
#pragma unroll
      for (int r = 0; r < 4; ++r) {
        const int tq = g * 4 + r;
#pragma unroll
        for (int cb = 0; cb < 2; ++cb) {
          int ts = ts0 + cb * 16 + cc;
          bool ok = (ts >= start_b) && (ts <= cur + tq);
          if (!ok) s[rb][cb][r] = -1e30f;
        }
        float tm = fmaxf(s[rb][0][r], s[rb][1][r]);
#pragma unroll
        for (int m = 1; m < 16; m <<= 1) tm = fmaxf(tm, __shfl_xor(tm, m, 64));
        float mn = fmaxf(mreg[rb][r], tm);
        float a = __expf(mreg[rb][r] - mn);
        float p0 = (s[rb][0][r] < -1e29f) ? 0.0f : __expf(s[rb][0][r] - mn);
        float p1 = (s[rb][1][r] < -1e29f) ? 0.0f : __expf(s[rb][1][r] - mn);
        s[rb][0][r] = p0; s[rb][1][r] = p1;
        float rs = p0 + p1;
#pragma unroll
        for (int m = 1; m < 16; m <<= 1) rs += __shfl_xor(rs, m, 64);
        lreg[rb][r] = lreg[rb][r] * a + rs;
        mreg[rb][r] = mn;
        al[rb][r] = a;
      }
    }
    // ---- P -> Kl overlay (K is dead after QK; in-wave DS is in-order)
    __builtin_amdgcn_wave_barrier();
#pragma unroll
    for (int rb = 0; rb < 2; ++rb)
#pragma unroll
      for (int cb = 0; cb < 2; ++cb)
#pragma unroll
        for (int r = 0; r < 4; ++r)
          Kl[wv][rb * 16 + g * 4 + r][cb * 16 + cc] = f2bf(s[rb][cb][r]);
    __builtin_amdgcn_wave_barrier();
    bf16x8 pf[2];
#pragma unroll
    for (int rb = 0; rb < 2; ++rb) {
      const unsigned short* pp = &Kl[wv][rb * 16 + cc][g * 8];
      uint2 lo = *(const uint2*)pp;
      uint2 hi = *(const uint2*)(pp + 4);
      pf[rb] = __builtin_bit_cast(bf16x8, make_uint4(lo.x, lo.y, hi.x, hi.y));
    }
    // ---- rescale + PV
#pragma unroll
    for (int rb = 0; rb < 2; ++rb)
#pragma unroll
      for (int hb = 0; hb < 8; ++hb) {
        f32x4 t = acc[rb][hb];
#pragma unroll
        for (int r = 0; r < 4; ++r) t[r] *= al[rb][r];
        acc[rb][hb] = mfma16(pf[rb], vf[hb], t);
      }
  }

  // ---- merge 4 wave-partials -> 1 block partial (scratch overlays Kl)
  float* Oscr = (float*)&Kl[0][0][0]; // 2 x 32 x 128 floats = 32 KB <= 33 KB
  auto dump = [&](int sid) {
#pragma unroll
    for (int rb = 0; rb < 2; ++rb)
#pragma unroll
      for (int hb = 0; hb < 8; ++hb)
#pragma unroll
        for (int r = 0; r < 4; ++r)
          Oscr[(sid * 32 + rb * 16 + g * 4 + r) * 128 + hb * 16 + cc] = acc[rb][hb][r];
    if (cc == 0) {
#pragma unroll
      for (int rb = 0; rb < 2; ++rb)
#pragma unroll
        for (int r = 0; r < 4; ++r) {
          mls[sid][rb * 16 + g * 4 + r][0] = mreg[rb][r];
          mls[sid][rb * 16 + g * 4 + r][1] = lreg[rb][r];
        }
    }
  };
  auto mergefrom = [&](int sid) {
    float a0s[2][4], a1s[2][4];
#pragma unroll
    for (int rb = 0; rb < 2; ++rb)
#pragma unroll
      for (int r = 0; r < 4; ++r) {
        int row = rb * 16 + g * 4 + r;
        float mp = mls[sid][row][0], lp = mls[sid][row][1];
        float M = fmaxf(mreg[rb][r], mp);
        float a0 = __expf(mreg[rb][r] - M), a1 = __expf(mp - M);
        lreg[rb][r] = lreg[rb][r] * a0 + lp * a1;
        mreg[rb][r] = M;
        a0s[rb][r] = a0; a1s[rb][r] = a1;
      }
#pragma unroll
    for (int rb = 0; rb < 2; ++rb)
#pragma unroll
      for (int hb = 0; hb < 8; ++hb)
#pragma unroll
        for (int r = 0; r < 4; ++r) {
          int row = rb * 16 + g * 4 + r;
          acc[rb][hb][r] = acc[rb][hb][r] * a0s[rb][r] +
                           Oscr[(sid * 32 + row) * 128 + hb * 16 + cc] * a1s[rb][r];
        }
  };
  __syncthreads();
  if (wv >= 2) dump(wv - 2);
  __syncthreads();
  if (wv < 2) mergefrom(wv);
  __syncthreads();
  if (wv == 1) dump(0);
  __syncthreads();
  if (wv == 0) {
    mergefrom(0);
    size_t pidx = (size_t)pair * NPART + qi;
#pragma unroll
    for (int rb = 0; rb < 2; ++rb)
#pragma unroll
      for (int hb = 0; hb < 8; ++hb)
#pragma unroll
        for (int r = 0; r < 4; ++r)
          partO[(pidx * 32 + rb * 16 + g * 4 + r) * 128 + hb * 16 + cc] = acc[rb][hb][r];
    if (cc == 0) {
#pragma unroll
      for (int rb = 0; rb < 2; ++rb)
#pragma unroll
        for (int r = 0; r < 4; ++r) {
          partML[pidx * 64 + (rb * 16 + g * 4 + r) * 2 + 0] = mreg[rb][r];
          partML[pidx * 64 + (rb * 16 + g * 4 + r) * 2 + 1] = lreg[rb][r];
        }
    }
  }
}

// ---------------------------------------------------------------------------
// Kernel D1: combine NPART partials per (b,kh). grid (64, 4).
// ---------------------------------------------------------------------------
__global__ __launch_bounds__(256) void k_combine(
    const float* __restrict__ partO, const float* __restrict__ partML,
    unsigned short* __restrict__ obf) {
  __shared__ float sc[NPART][32];
  const int pair = blockIdx.x, b = pair >> 3, kh = pair & 7;
  const int isub = blockIdx.y;
  const int tid = threadIdx.x;
  if (tid < 32) {
    float mm[NPART], ll[NPART];
    float M = -3.0e38f;
#pragma unroll
    for (int p = 0; p < NPART; ++p) {
      mm[p] = partML[((size_t)pair * NPART + p) * 64 + tid * 2 + 0];
      ll[p] = partML[((size_t)pair * NPART + p) * 64 + tid * 2 + 1];
      M = fmaxf(M, mm[p]);
    }
    float denom = 0.0f;
#pragma unroll
    for (int p = 0; p < NPART; ++p) denom += __expf(mm[p] - M) * ll[p];
    float inv = (denom > 0.0f) ? 1.0f / denom : 0.0f;
#pragma unroll
    for (int p = 0; p < NPART; ++p) sc[p][tid] = __expf(mm[p] - M) * inv;
  }
  __syncthreads();
#pragma unroll
  for (int i = 0; i < 4; ++i) {
    int idx = tid + ((isub * 4 + i) << 8);
    int row = idx >> 7, hc = idx & 127;
    float o = 0.0f;
#pragma unroll
    for (int p = 0; p < NPART; ++p)
      o += partO[(((size_t)pair * NPART + p) * 32 + row) * 128 + hc] * sc[p][row];
    int gq = row >> 4, t = row & 15, n = kh * 2 + gq;
    obf[((b * TT + t) * NN + n) * 128 + hc] = f2bf(o);
  }
}

// ---------------------------------------------------------------------------
// Kernel D2: output projection, LDS-free / barrier-free. (unchanged)
// ---------------------------------------------------------------------------
__global__ __launch_bounds__(256) void k_out_gemm(
    const unsigned short* __restrict__ obf, const unsigned short* __restrict__ Wt2,
    float* __restrict__ out) {
  const int tid = threadIdx.x, lane = tid & 63, wv = tid >> 6;
  const int cc = lane & 15, g = lane >> 4;
  const int m0 = blockIdx.x * 32, n0 = blockIdx.y * 64;
  const int rt = wv >> 1, cb0 = (wv & 1) * 32;
  const int m = m0 + rt * 16 + cc;
  f32x4 acc[2];
#pragma unroll
  for (int i = 0; i < 2; ++i) acc[i] = (f32x4)0.0f;

#pragma unroll 4
  for (int k0 = 0; k0 < 2048; k0 += 32) {
    bf16x8 af = *(const bf16x8*)(obf + (size_t)m * 2048 + k0 + g * 8);
#pragma unroll
    for (int ct = 0; ct < 2; ++ct) {
      const int d = n0 + cb0 + ct * 16 + cc;
      bf16x8 bf = *(const bf16x8*)(Wt2 + (size_t)d * 2048 + k0 + g * 8);
      acc[ct] = mfma16(af, bf, acc[ct]);
    }
  }
#pragma unroll
  for (int ct = 0; ct < 2; ++ct)
#pragma unroll
    for (int r = 0; r < 4; ++r)
      out[(size_t)(m0 + rt * 16 + g * 4 + r) * 1024 + n0 + cb0 + ct * 16 + cc] = acc[ct][r];
}

// ---------------------------------------------------------------------------
extern "C" void kernel_launch(void* const* d_in, const int* in_sizes, int n_in,
                              void* d_out, int out_size, void* d_ws, size_t ws_size,
                              hipStream_t stream) {
  (void)in_sizes; (void)n_in; (void)out_size; (void)ws_size;
  const float* x   = (const float*)d_in[0];
  const float* Wq  = (const float*)d_in[1];
  const float* Wk  = (const float*)d_in[2];
  const float* Wv  = (const float*)d_in[3];
  const float* Wo  = (const float*)d_in[4];
  const float* qs  = (const float*)d_in[5];
  const float* ks  = (const float*)d_in[6];
  const float* kc  = (const float*)d_in[7];
  const float* vc  = (const float*)d_in[8];
  const int* seg   = (const int*)d_in[9];
  const int* sind  = (const int*)d_in[10];
  const int* curp  = (const int*)d_in[11];
  float* out = (float*)d_out;

  char* ws = (char*)d_ws;
  float*          qkv    = (float*)(ws + 0);                 //  2,097,152 B
  unsigned short* qa     = (unsigned short*)(ws + 2097152);  //    524,288 B
  unsigned short* ka     = (unsigned short*)(ws + 2621440);  //    262,144 B
  unsigned short* va     = (unsigned short*)(ws + 2883584);  //    262,144 B
  float*          partO  = (float*)(ws + 3145728);           // 16,777,216 B
  float*          partML = (float*)(ws + 19922944);          //    262,144 B
  unsigned short* obf    = (unsigned short*)(ws + 20185088); //    524,288 B
  unsigned short* Wt1    = (unsigned short*)(ws + 20709376); //  8,388,608 B
  unsigned short* Wt2    = (unsigned short*)(ws + 29097984); //  4,194,304 B

  k_wtrans<<<dim3(32, 32, 4), 256, 0, stream>>>(Wq, Wk, Wv, Wo, Wt1, Wt2);
  k_qkv_gemm<<<dim3(4, 32), 256, 0, stream>>>(x, Wt1, qkv);
  k_normrope<<<dim3(128, 32), 128, 0, stream>>>(qkv, qs, ks, seg, curp, qa, ka, va);
  k_attn<<<dim3(64, NPART), 256, 0, stream>>>(kc, vc, qa, ka, va, seg, sind, curp, partO, partML);
  k_combine<<<dim3(64, 4), 256, 0, stream>>>(partO, partML, obf);
  k_out_gemm<<<dim3(4, 16), 256, 0, stream>>>(obf, Wt2, out);
}